// Round 4
// baseline (167.580 us; speedup 1.0000x reference)
//
#include <hip/hip_runtime.h>

// Bilateral 5x5, 3 chained passes on [32,1,512,512] fp32, replicate padding.
// w(dr,dc) = exp2( dr^2*nax + dc^2*nay + d^2*ncr ), -log2e pre-folded.
//
// Round-3 lesson: compute (pruned 3x3, 8 exps/px) is ~10 us/pass at issue
// rate, but the LDS staging machinery (9-iter scalar staging loop, barrier,
// 15 ds_read_b128, 4.2M conflict cycles) kept passes at ~41 us. This round
// removes LDS entirely: each thread's window is 3 rows x aligned float4
// triples read straight from global (9 dwordx4, hoisted), row addresses are
// wave-uniform, x-edge replication is 2 cndmasks/row on pre-clamped offsets.
// L1 absorbs the overlap between neighboring threads/rows.
//
// Fast path (uniform branch): all |dr|=2 / |dc|=2 taps spatially pruned
// (4*nax < TH2 && 4*nay < TH2) -> 3x3, 9 loads. Slow path: generic 5x5
// direct-load with per-tap uniform pruning (round-3 semantics). Dropped
// spatial mass <= ~1.7e-3/pass for sigma=0.5 (measured absmax 3.9e-3, same
// as unpruned round 1).

#define HWIN 2
#define TX   64
#define TY   4
#define PXT  4
#define TILE_W (TX * PXT)           // 256 output cols per block

#if __has_builtin(__builtin_amdgcn_exp2f)
#define EXP2(x) __builtin_amdgcn_exp2f(x)
#else
#define EXP2(x) exp2f(x)
#endif
#if __has_builtin(__builtin_amdgcn_rcpf)
#define RCP(x) __builtin_amdgcn_rcpf(x)
#else
#define RCP(x) (1.0f / (x))
#endif

#define TH2 (-10.0f)   // prune taps with spatial weight < 2^TH2

__global__ __launch_bounds__(256)
void bilat_pass(const float* __restrict__ in, float* __restrict__ out,
                const float* __restrict__ sxyz, const float* __restrict__ srr,
                int pass, int H, int W)
{
    const int tx = threadIdx.x, ty = threadIdx.y;
    int c = blockIdx.x * TILE_W + PXT * tx;      // first of 4 output cols
    const int oy = blockIdx.y * TY + ty;         // output row (uniform/wave)
    if (oy >= H) return;                         // no barrier -> safe
    if (c > W - PXT) c = W - PXT;                // assumes W % 4 == 0

    const size_t img_off = (size_t)blockIdx.z * (size_t)H * (size_t)W;
    const float* __restrict__ img = in + img_off;

    // ---- per-pass constants (SGPR), -log2e pre-folded ----
    const float sx = sxyz[2 * pass + 0];
    const float sy = sxyz[2 * pass + 1];
    const float sr = srr[pass];
    const float L2E = 1.4426950408889634f;
    const float ncr = -0.5f / (sr * sr) * L2E;   // * d^2
    const float nax = -0.5f / (sx * sx) * L2E;   // * dr^2
    const float nay = -0.5f / (sy * sy) * L2E;   // * dc^2

    // ---- x-edge replicate handling: pre-clamped aligned load columns ----
    const bool ledge = (c - 4 < 0);              // only c==0
    const bool redge = (c + 4 > W - 4);          // only c==W-4
    const int colL = ledge ? 0 : c - 4;          // L quad: cols colL..colL+3
    const int colR = redge ? W - 4 : c + 4;      // R quad

    float cen[4], num[4], den[4];

    const bool prune2 = (4.0f * nax < TH2) && (4.0f * nay < TH2);
    if (prune2) {
        // ================= fast path: effective 3x3, 9 hoisted loads ======
        const int rm = max(oy - 1, 0);
        const int rp = min(oy + 1, H - 1);
        const float* p0 = img + (size_t)oy * W;
        const float* pm = img + (size_t)rm * W;
        const float* pp = img + (size_t)rp * W;

        const float4 Lm = *(const float4*)(pm + colL);
        const float4 Mm = *(const float4*)(pm + c);
        const float4 Rm = *(const float4*)(pm + colR);
        const float4 L0 = *(const float4*)(p0 + colL);
        const float4 M0 = *(const float4*)(p0 + c);
        const float4 R0 = *(const float4*)(p0 + colR);
        const float4 Lp = *(const float4*)(pp + colL);
        const float4 Mp = *(const float4*)(pp + c);
        const float4 Rp = *(const float4*)(pp + colR);

        cen[0] = M0.x; cen[1] = M0.y; cen[2] = M0.z; cen[3] = M0.w;
        num[0] = cen[0]; num[1] = cen[1]; num[2] = cen[2]; num[3] = cen[3];
        den[0] = den[1] = den[2] = den[3] = 1.0f;   // center tap, w == 1

        const float b_ax  = nax;                 // (dr=+-1, dc=0)
        const float b_ay  = nay;                 // (dr=0, dc=+-1)
        const float b_diag = nax + nay;          // (dr=+-1, dc=+-1)

        // w6[k] = col c-1+k ; k in 0..5
        #define TAPS_ROW3(L, M, R, B_M1, B_0, B_P1, SKIP0)                   \
        do {                                                                  \
            float w6[6];                                                      \
            w6[0] = ledge ? (L).x : (L).w;                                    \
            w6[1] = (M).x; w6[2] = (M).y; w6[3] = (M).z; w6[4] = (M).w;       \
            w6[5] = redge ? (R).w : (R).x;                                    \
            _Pragma("unroll")                                                 \
            for (int dc = -1; dc <= 1; ++dc) {                                \
                if (SKIP0 && dc == 0) continue;                               \
                const float base = (dc == -1) ? (B_M1)                        \
                                 : (dc == 0)  ? (B_0) : (B_P1);               \
                _Pragma("unroll")                                             \
                for (int j = 0; j < PXT; ++j) {                               \
                    const float nb = w6[1 + j + dc];                          \
                    const float d  = nb - cen[j];                             \
                    const float t  = fmaf(d * d, ncr, base);                  \
                    const float w  = EXP2(t);                                 \
                    num[j] = fmaf(w, nb, num[j]);                             \
                    den[j] += w;                                              \
                }                                                             \
            }                                                                 \
        } while (0)

        TAPS_ROW3(L0, M0, R0, b_ay,   0.0f, b_ay,   true);   // dr = 0
        TAPS_ROW3(Lm, Mm, Rm, b_diag, b_ax, b_diag, false);  // dr = -1
        TAPS_ROW3(Lp, Mp, Rp, b_diag, b_ax, b_diag, false);  // dr = +1
        #undef TAPS_ROW3
    } else {
        // ================= slow path: generic 5x5, per-tap uniform prune ==
        const float4 Mc = *(const float4*)(img + (size_t)oy * W + c);
        cen[0] = Mc.x; cen[1] = Mc.y; cen[2] = Mc.z; cen[3] = Mc.w;
        num[0] = cen[0]; num[1] = cen[1]; num[2] = cen[2]; num[3] = cen[3];
        den[0] = den[1] = den[2] = den[3] = 1.0f;

        #pragma unroll
        for (int dr = -HWIN; dr <= HWIN; ++dr) {
            const float ra = (float)(dr * dr) * nax;
            const float rbest = dr ? ra : nay;
            if (rbest < TH2) continue;                 // uniform row skip
            const int gy = min(max(oy + dr, 0), H - 1);
            const float* pr = img + (size_t)gy * W;
            const float4 L = *(const float4*)(pr + colL);
            const float4 M = *(const float4*)(pr + c);
            const float4 R = *(const float4*)(pr + colR);
            // w8[k] = col c-2+k ; k in 0..7
            float w8[8];
            w8[0] = ledge ? L.x : L.z;
            w8[1] = ledge ? L.x : L.w;
            w8[2] = M.x; w8[3] = M.y; w8[4] = M.z; w8[5] = M.w;
            w8[6] = redge ? R.w : R.x;
            w8[7] = redge ? R.w : R.y;
            #pragma unroll
            for (int dc = -HWIN; dc <= HWIN; ++dc) {
                if (dr == 0 && dc == 0) continue;      // center done
                const float base = ra + (float)(dc * dc) * nay;
                if (base < TH2) continue;              // uniform tap skip
                #pragma unroll
                for (int j = 0; j < PXT; ++j) {
                    const float nb = w8[2 + j + dc];
                    const float d  = nb - cen[j];
                    const float t  = fmaf(d * d, ncr, base);
                    const float w  = EXP2(t);
                    num[j] = fmaf(w, nb, num[j]);
                    den[j] += w;
                }
            }
        }
    }

    // ---- store (c % 4 == 0, in-bounds by construction) ----
    float4 o;
    o.x = num[0] * RCP(den[0]);
    o.y = num[1] * RCP(den[1]);
    o.z = num[2] * RCP(den[2]);
    o.w = num[3] * RCP(den[3]);
    *(float4*)&out[img_off + (size_t)oy * W + c] = o;
}

extern "C" void kernel_launch(void* const* d_in, const int* in_sizes, int n_in,
                              void* d_out, int out_size, void* d_ws, size_t ws_size,
                              hipStream_t stream)
{
    const float* x    = (const float*)d_in[0];
    const float* sxyz = (const float*)d_in[1];   // [3,2]
    const float* sr   = (const float*)d_in[2];   // [3]
    float* out = (float*)d_out;
    float* tmp = (float*)d_ws;                   // 33.5 MB scratch

    const int H = 512, W = 512;
    const int BC = in_sizes[0] / (H * W);        // 32

    dim3 block(TX, TY);
    dim3 grid((W + TILE_W - 1) / TILE_W, (H + TY - 1) / TY, BC);

    // pass 0: x -> out ; pass 1: out -> tmp ; pass 2: tmp -> out
    bilat_pass<<<grid, block, 0, stream>>>(x,   out, sxyz, sr, 0, H, W);
    bilat_pass<<<grid, block, 0, stream>>>(out, tmp, sxyz, sr, 1, H, W);
    bilat_pass<<<grid, block, 0, stream>>>(tmp, out, sxyz, sr, 2, H, W);
}

// Round 5
// 157.545 us; speedup vs baseline: 1.0637x; 1.0637x over previous
//
#include <hip/hip_runtime.h>

// Bilateral 5x5, 3 chained passes FUSED into one kernel.
// [32,1,512,512] fp32, replicate padding, w = exp2(dr^2*nax + dc^2*nay + d^2*ncr).
//
// Round-4 lesson: 3 separate dispatches each sat at ~41 us regardless of
// structure (LDS-staged == direct-global) while the issue-rate model says
// ~10-12 us of work -> the floor is per-dispatch / inter-pass, not staging.
// Fusion: each block computes a 64x64 output tile end-to-end through LDS
// with halo recompute (+22% px), removing 2 dispatch boundaries and
// 2x67 MB of inter-pass HBM traffic.
//
// Geometry (all offsets chosen so every pass reads 16B-aligned LDS quads
// with center at (row+2, 4q+4) -- clamp-free inner loops):
//   buf0 staged input : rows [Y0-6,Y0+69] x cols [X0-12,X0+79]  76 x 92
//   buf1 = pass1 out  : rows [Y0-4,Y0+67] x cols [X0- 8,X0+75]  72 x 84
//   buf2 = pass2 out  : rows [Y0-2,Y0+65] x cols [X0- 4,X0+71]  68 x 76 (aliases buf0)
// Staging clamps global coords -> buf0 is replicate-padded exactly.
// After pass1/pass2, replicate_fill() copies edge rows/cols in border
// blocks so buf1/buf2 are replicate-padded exactly too (reference pads the
// intermediate images, not the input).
//
// Pruning (unchanged from round 3): spatial weights are per-pass constants;
// taps with spatial log2-weight < TH2 are skipped -> effective 3x3 for
// sigma=0.5 (8 exps/px). Generic 5x5 path kept for large sigma.

#define EXP2(x) __builtin_amdgcn_exp2f(x)
#define RCP(x)  __builtin_amdgcn_rcpf(x)
#define TH2 (-10.0f)

#define TILE 64
#define S0R 76
#define S0C 92            // 368 B row stride (16B-aligned)
#define S1R 72
#define S1C 84            // 336 B
#define S2R 68
#define S2C 76            // 304 B

// Copy replicate-padding into phantom slots of an LDS image.
// Valid region is [rlo,rhi] x [vlo,vhi]; reads only valid slots, writes only
// phantom slots -> race-free without an internal barrier. Block-uniform
// early-out for interior blocks.
template<int NR, int NC>
__device__ __forceinline__ void replicate_fill(float* buf, int rlo, int rhi,
                                               int vlo, int vhi, int tid)
{
    if (rlo == 0 && vlo == 0 && rhi == NR - 1 && vhi == NC - 1) return;
    for (int t = tid; t < NR * NC; t += 256) {
        const int r = t / NC, v = t - r * NC;
        const int rs = min(max(r, rlo), rhi);
        const int vs = min(max(v, vlo), vhi);
        if (rs != r || vs != v) buf[r * NC + v] = buf[rs * NC + vs];
    }
}

// One bilateral pass over a tile held in LDS.
// Unit t -> (row r, quad q); center quad at src[(r+2)*SST + 4q+4].
// Output: LDS dst[(r)*DSTST + 4q] or global gout[r*W + 4q].
template<int NQ, int NR, int SST, int DSTST, bool TOG>
__device__ __forceinline__ void bilat_tile_pass(
    const float* __restrict__ src, float* __restrict__ dst,
    float* __restrict__ gout, int W,
    int tid, float ncr, float nax, float nay, bool prune)
{
    for (int t = tid; t < NQ * NR; t += 256) {
        const int r = t / NQ;
        const int q = t - r * NQ;
        const float* cp = src + (r + 2) * SST + 4 * q + 4;
        const float4 M0 = *(const float4*)cp;
        float cen[4] = {M0.x, M0.y, M0.z, M0.w};
        float num[4] = {M0.x, M0.y, M0.z, M0.w};
        float den[4] = {1.f, 1.f, 1.f, 1.f};

        auto tap6 = [&](const float* w6, int dc, float base) {
            #pragma unroll
            for (int j = 0; j < 4; ++j) {
                const float nb = w6[1 + j + dc];
                const float d  = nb - cen[j];
                const float tt = fmaf(d * d, ncr, base);
                const float w  = EXP2(tt);
                num[j] = fmaf(w, nb, num[j]);
                den[j] += w;
            }
        };

        if (prune) {
            // effective 3x3 (sigma small): 8 taps
            {   // dr = 0
                float w6[6] = {cp[-1], M0.x, M0.y, M0.z, M0.w, cp[4]};
                tap6(w6, -1, nay);
                tap6(w6, +1, nay);
            }
            #pragma unroll
            for (int s = 0; s < 2; ++s) {   // dr = -1, +1
                const float* rp = cp + (s ? SST : -SST);
                const float4 Mr = *(const float4*)rp;
                float w6[6] = {rp[-1], Mr.x, Mr.y, Mr.z, Mr.w, rp[4]};
                tap6(w6, -1, nax + nay);
                tap6(w6,  0, nax);
                tap6(w6, +1, nax + nay);
            }
        } else {
            // generic 5x5 with per-tap uniform pruning
            #pragma unroll
            for (int dr = -2; dr <= 2; ++dr) {
                const float ra = (float)(dr * dr) * nax;
                const float rbest = dr ? ra : nay;
                if (rbest < TH2) continue;
                const float* rp = cp + dr * SST;
                const float2 eL = *(const float2*)(rp - 2);
                const float4 Mr = *(const float4*)rp;
                const float2 eR = *(const float2*)(rp + 4);
                const float w8[8] = {eL.x, eL.y, Mr.x, Mr.y, Mr.z, Mr.w,
                                     eR.x, eR.y};
                #pragma unroll
                for (int dc = -2; dc <= 2; ++dc) {
                    if (dr == 0 && dc == 0) continue;
                    const float base = ra + (float)(dc * dc) * nay;
                    if (base < TH2) continue;
                    #pragma unroll
                    for (int j = 0; j < 4; ++j) {
                        const float nb = w8[2 + j + dc];
                        const float d  = nb - cen[j];
                        const float tt = fmaf(d * d, ncr, base);
                        const float w  = EXP2(tt);
                        num[j] = fmaf(w, nb, num[j]);
                        den[j] += w;
                    }
                }
            }
        }

        float4 o;
        o.x = num[0] * RCP(den[0]);
        o.y = num[1] * RCP(den[1]);
        o.z = num[2] * RCP(den[2]);
        o.w = num[3] * RCP(den[3]);
        if (TOG) *(float4*)(gout + r * W + 4 * q) = o;
        else     *(float4*)(dst + r * DSTST + 4 * q) = o;
    }
}

__global__ __launch_bounds__(256)
void bilat3_fused(const float* __restrict__ in, float* __restrict__ out,
                  const float* __restrict__ sxyz, const float* __restrict__ srr,
                  int H, int W)
{
    __shared__ __align__(16) float buf0[S0R * S0C];   // 27968 B
    __shared__ __align__(16) float buf1[S1R * S1C];   // 24192 B

    const int tid = threadIdx.x;
    const int X0 = blockIdx.x * TILE;
    const int Y0 = blockIdx.y * TILE;
    const size_t img_off = (size_t)blockIdx.z * (size_t)H * (size_t)W;
    const float* __restrict__ img = in + img_off;

    // per-pass constants, -log2e pre-folded
    const float L2E = 1.4426950408889634f;
    float ncr[3], nax[3], nay[3];
    bool prune[3];
    #pragma unroll
    for (int p = 0; p < 3; ++p) {
        const float sx = sxyz[2 * p], sy = sxyz[2 * p + 1], sr = srr[p];
        ncr[p] = -0.5f / (sr * sr) * L2E;
        nax[p] = -0.5f / (sx * sx) * L2E;
        nay[p] = -0.5f / (sy * sy) * L2E;
        prune[p] = (4.f * nax[p] < TH2) && (4.f * nay[p] < TH2);
    }

    // ---- stage buf0: replicate-clamped input aperture ----
    {
        const int NQ0 = S0C / 4;  // 23 quads/row
        for (int t = tid; t < S0R * NQ0; t += 256) {
            const int r = t / NQ0, k = t - r * NQ0;
            const int gy = Y0 - 6 + r;
            const int gx = X0 - 12 + 4 * k;
            float4 v;
            if (gy >= 0 && gy < H && gx >= 0 && gx + 3 < W) {
                v = *(const float4*)(img + (size_t)gy * W + gx);  // 16B-aligned
            } else {
                const size_t rb = (size_t)min(max(gy, 0), H - 1) * W;
                v.x = img[rb + min(max(gx    , 0), W - 1)];
                v.y = img[rb + min(max(gx + 1, 0), W - 1)];
                v.z = img[rb + min(max(gx + 2, 0), W - 1)];
                v.w = img[rb + min(max(gx + 3, 0), W - 1)];
            }
            *(float4*)(buf0 + r * S0C + 4 * k) = v;
        }
    }
    __syncthreads();

    // ---- pass 1: buf0 -> buf1 ----
    bilat_tile_pass<S1C / 4, S1R, S0C, S1C, false>(
        buf0, buf1, nullptr, W, tid, ncr[0], nax[0], nay[0], prune[0]);
    __syncthreads();
    replicate_fill<S1R, S1C>(buf1,
        max(0, 4 - Y0), min(S1R - 1, (H - 1) - (Y0 - 4)),
        max(0, 8 - X0), min(S1C - 1, (W - 1) - (X0 - 8)), tid);
    __syncthreads();

    // ---- pass 2: buf1 -> buf2 (aliases buf0; pass-1 reads are done) ----
    float* buf2 = buf0;
    bilat_tile_pass<S2C / 4, S2R, S1C, S2C, false>(
        buf1, buf2, nullptr, W, tid, ncr[1], nax[1], nay[1], prune[1]);
    __syncthreads();
    replicate_fill<S2R, S2C>(buf2,
        max(0, 2 - Y0), min(S2R - 1, (H - 1) - (Y0 - 2)),
        max(0, 4 - X0), min(S2C - 1, (W - 1) - (X0 - 4)), tid);
    __syncthreads();

    // ---- pass 3: buf2 -> global ----
    float* gout = out + img_off + (size_t)Y0 * W + X0;
    bilat_tile_pass<TILE / 4, TILE, S2C, 0, true>(
        buf2, nullptr, gout, W, tid, ncr[2], nax[2], nay[2], prune[2]);
}

extern "C" void kernel_launch(void* const* d_in, const int* in_sizes, int n_in,
                              void* d_out, int out_size, void* d_ws, size_t ws_size,
                              hipStream_t stream)
{
    const float* x    = (const float*)d_in[0];
    const float* sxyz = (const float*)d_in[1];   // [3,2]
    const float* sr   = (const float*)d_in[2];   // [3]
    float* out = (float*)d_out;
    (void)d_ws; (void)ws_size;

    const int H = 512, W = 512;
    const int BC = in_sizes[0] / (H * W);        // 32

    dim3 block(256);
    dim3 grid(W / TILE, H / TILE, BC);           // 8 x 8 x 32 = 2048 blocks

    bilat3_fused<<<grid, block, 0, stream>>>(x, out, sxyz, sr, H, W);
}

// Round 6
// 152.342 us; speedup vs baseline: 1.1000x; 1.0342x over previous
//
#include <hip/hip_runtime.h>

// Bilateral 5x5, 3 chained passes FUSED into one kernel.
// [32,1,512,512] fp32, replicate padding, w = exp2(dr^2*nax + dc^2*nay + d^2*ncr).
//
// Round-5 lesson (counters): the fused 64x64 version stalled on
// (a) 16.6M LDS bank-conflict cycles -- scalar ds_read_b32 edge reads at
//     16B lane stride are an inherent 8-way conflict (~30% of runtime);
// (b) 26% occupancy -- 52 KB LDS allowed only 3 blocks/CU.
// This round: all LDS window reads are aligned ds_read_b128 L/M/R quads
// (consecutive lanes -> sequential banks, conflict-free), and the tile is
// 64x32 with 29.6 KB LDS -> 5 blocks/CU (20 waves). Halo recompute rises
// to 1.33x (vs 1.22x at 64x64) -- paid for by latency hiding.
//
// Geometry (every pass reads 16B-aligned LDS quads, center at (r+2, 4q+4)):
//   buf0 staged input : rows [Y0-6,Y0+37] x cols [X0-12,X0+79]  44 x 92
//   buf1 = pass1 out  : rows [Y0-4,Y0+35] x cols [X0- 8,X0+75]  40 x 84
//   buf2 = pass2 out  : rows [Y0-2,Y0+33] x cols [X0- 4,X0+71]  36 x 76 (aliases buf0)
// Staging clamps global coords (buf0 replicate-padded exactly); after
// pass1/pass2 replicate_fill() restores replicate padding of intermediates
// in border blocks (the reference pads each intermediate image).
//
// Pruning (round 3): spatial weights are per-pass constants; taps with
// spatial log2-weight < TH2 are skipped -> effective 3x3 for sigma=0.5
// (8 exps/px). Generic 5x5 path kept for large sigma.

#define EXP2(x) __builtin_amdgcn_exp2f(x)
#define RCP(x)  __builtin_amdgcn_rcpf(x)
#define TH2 (-10.0f)

#define TILE_X 64
#define TILE_Y 32
#define S0R 44
#define S0C 92            // 368 B row stride (16B-aligned)
#define S1R 40
#define S1C 84            // 336 B
#define S2R 36
#define S2C 76            // 304 B

// Copy replicate-padding into phantom slots of an LDS image.
// Valid region [rlo,rhi]x[vlo,vhi]; reads valid slots, writes phantom slots
// -> race-free without an internal barrier. Block-uniform early-out.
template<int NR, int NC>
__device__ __forceinline__ void replicate_fill(float* buf, int rlo, int rhi,
                                               int vlo, int vhi, int tid)
{
    if (rlo == 0 && vlo == 0 && rhi == NR - 1 && vhi == NC - 1) return;
    for (int t = tid; t < NR * NC; t += 256) {
        const int r = t / NC, v = t - r * NC;
        const int rs = min(max(r, rlo), rhi);
        const int vs = min(max(v, vlo), vhi);
        if (rs != r || vs != v) buf[r * NC + v] = buf[rs * NC + vs];
    }
}

// One bilateral pass over a tile held in LDS.
// Unit t -> (row r, quad q); center quad at src[(r+2)*SST + 4q+4].
// All LDS reads are aligned b128 (L/M/R quads) -> no bank conflicts.
template<int NQ, int NR, int SST, int DSTST, bool TOG>
__device__ __forceinline__ void bilat_tile_pass(
    const float* __restrict__ src, float* __restrict__ dst,
    float* __restrict__ gout, int W,
    int tid, float ncr, float nax, float nay, bool prune)
{
    #pragma unroll
    for (int t = tid; t < NQ * NR; t += 256) {
        const int r = t / NQ;              // NQ=16 for pass3 -> shift only
        const int q = t - r * NQ;
        const float* cp = src + (r + 2) * SST + 4 * q + 4;
        const float4 M0 = *(const float4*)cp;
        float cen[4] = {M0.x, M0.y, M0.z, M0.w};
        float num[4] = {M0.x, M0.y, M0.z, M0.w};
        float den[4] = {1.f, 1.f, 1.f, 1.f};

        auto tap6 = [&](const float* w6, int dc, float base) {
            #pragma unroll
            for (int j = 0; j < 4; ++j) {
                const float nb = w6[1 + j + dc];
                const float d  = nb - cen[j];
                const float tt = fmaf(d * d, ncr, base);
                const float w  = EXP2(tt);
                num[j] = fmaf(w, nb, num[j]);
                den[j] += w;
            }
        };

        if (prune) {
            // effective 3x3: 8 taps, 7 b128 reads, all conflict-free
            {   // dr = 0 (center quad already in M0)
                const float4 Lq = *(const float4*)(cp - 4);
                const float4 Rq = *(const float4*)(cp + 4);
                const float w6[6] = {Lq.w, M0.x, M0.y, M0.z, M0.w, Rq.x};
                tap6(w6, -1, nay);
                tap6(w6, +1, nay);
            }
            #pragma unroll
            for (int s = 0; s < 2; ++s) {   // dr = -1, +1
                const float* rp = cp + (s ? SST : -SST);
                const float4 Lq = *(const float4*)(rp - 4);
                const float4 Mq = *(const float4*)(rp);
                const float4 Rq = *(const float4*)(rp + 4);
                const float w6[6] = {Lq.w, Mq.x, Mq.y, Mq.z, Mq.w, Rq.x};
                tap6(w6, -1, nax + nay);
                tap6(w6,  0, nax);
                tap6(w6, +1, nax + nay);
            }
        } else {
            // generic 5x5 with per-tap uniform pruning
            #pragma unroll
            for (int dr = -2; dr <= 2; ++dr) {
                const float ra = (float)(dr * dr) * nax;
                const float rbest = dr ? ra : nay;
                if (rbest < TH2) continue;
                const float* rp = cp + dr * SST;
                const float4 Lq = *(const float4*)(rp - 4);
                const float4 Mq = *(const float4*)(rp);
                const float4 Rq = *(const float4*)(rp + 4);
                const float w8[8] = {Lq.z, Lq.w, Mq.x, Mq.y, Mq.z, Mq.w,
                                     Rq.x, Rq.y};
                #pragma unroll
                for (int dc = -2; dc <= 2; ++dc) {
                    if (dr == 0 && dc == 0) continue;
                    const float base = ra + (float)(dc * dc) * nay;
                    if (base < TH2) continue;
                    #pragma unroll
                    for (int j = 0; j < 4; ++j) {
                        const float nb = w8[2 + j + dc];
                        const float d  = nb - cen[j];
                        const float tt = fmaf(d * d, ncr, base);
                        const float w  = EXP2(tt);
                        num[j] = fmaf(w, nb, num[j]);
                        den[j] += w;
                    }
                }
            }
        }

        float4 o;
        o.x = num[0] * RCP(den[0]);
        o.y = num[1] * RCP(den[1]);
        o.z = num[2] * RCP(den[2]);
        o.w = num[3] * RCP(den[3]);
        if (TOG) *(float4*)(gout + r * W + 4 * q) = o;
        else     *(float4*)(dst + r * DSTST + 4 * q) = o;
    }
}

__global__ __launch_bounds__(256)
void bilat3_fused(const float* __restrict__ in, float* __restrict__ out,
                  const float* __restrict__ sxyz, const float* __restrict__ srr,
                  int H, int W)
{
    __shared__ __align__(16) float buf0[S0R * S0C];   // 16192 B
    __shared__ __align__(16) float buf1[S1R * S1C];   // 13440 B -> 29.6 KB

    const int tid = threadIdx.x;
    const int X0 = blockIdx.x * TILE_X;
    const int Y0 = blockIdx.y * TILE_Y;
    const size_t img_off = (size_t)blockIdx.z * (size_t)H * (size_t)W;
    const float* __restrict__ img = in + img_off;

    // per-pass constants, -log2e pre-folded
    const float L2E = 1.4426950408889634f;
    float ncr[3], nax[3], nay[3];
    bool prune[3];
    #pragma unroll
    for (int p = 0; p < 3; ++p) {
        const float sx = sxyz[2 * p], sy = sxyz[2 * p + 1], sr = srr[p];
        ncr[p] = -0.5f / (sr * sr) * L2E;
        nax[p] = -0.5f / (sx * sx) * L2E;
        nay[p] = -0.5f / (sy * sy) * L2E;
        prune[p] = (4.f * nax[p] < TH2) && (4.f * nay[p] < TH2);
    }

    // ---- stage buf0: replicate-clamped input aperture ----
    {
        const int NQ0 = S0C / 4;  // 23 quads/row
        #pragma unroll
        for (int t = tid; t < S0R * NQ0; t += 256) {
            const int r = t / NQ0, k = t - r * NQ0;
            const int gy = Y0 - 6 + r;
            const int gx = X0 - 12 + 4 * k;
            float4 v;
            if (gy >= 0 && gy < H && gx >= 0 && gx + 3 < W) {
                v = *(const float4*)(img + (size_t)gy * W + gx);  // aligned
            } else {
                const size_t rb = (size_t)min(max(gy, 0), H - 1) * W;
                v.x = img[rb + min(max(gx    , 0), W - 1)];
                v.y = img[rb + min(max(gx + 1, 0), W - 1)];
                v.z = img[rb + min(max(gx + 2, 0), W - 1)];
                v.w = img[rb + min(max(gx + 3, 0), W - 1)];
            }
            *(float4*)(buf0 + r * S0C + 4 * k) = v;
        }
    }
    __syncthreads();

    // ---- pass 1: buf0 -> buf1 ----
    bilat_tile_pass<S1C / 4, S1R, S0C, S1C, false>(
        buf0, buf1, nullptr, W, tid, ncr[0], nax[0], nay[0], prune[0]);
    __syncthreads();
    replicate_fill<S1R, S1C>(buf1,
        max(0, 4 - Y0), min(S1R - 1, (H - 1) - (Y0 - 4)),
        max(0, 8 - X0), min(S1C - 1, (W - 1) - (X0 - 8)), tid);
    __syncthreads();

    // ---- pass 2: buf1 -> buf2 (aliases buf0; staged input is dead) ----
    float* buf2 = buf0;
    bilat_tile_pass<S2C / 4, S2R, S1C, S2C, false>(
        buf1, buf2, nullptr, W, tid, ncr[1], nax[1], nay[1], prune[1]);
    __syncthreads();
    replicate_fill<S2R, S2C>(buf2,
        max(0, 2 - Y0), min(S2R - 1, (H - 1) - (Y0 - 2)),
        max(0, 4 - X0), min(S2C - 1, (W - 1) - (X0 - 4)), tid);
    __syncthreads();

    // ---- pass 3: buf2 -> global (512 units = 2 x 256, div-free) ----
    float* gout = out + img_off + (size_t)Y0 * W + X0;
    bilat_tile_pass<TILE_X / 4, TILE_Y, S2C, 0, true>(
        buf2, nullptr, gout, W, tid, ncr[2], nax[2], nay[2], prune[2]);
}

extern "C" void kernel_launch(void* const* d_in, const int* in_sizes, int n_in,
                              void* d_out, int out_size, void* d_ws, size_t ws_size,
                              hipStream_t stream)
{
    const float* x    = (const float*)d_in[0];
    const float* sxyz = (const float*)d_in[1];   // [3,2]
    const float* sr   = (const float*)d_in[2];   // [3]
    float* out = (float*)d_out;
    (void)d_ws; (void)ws_size;

    const int H = 512, W = 512;
    const int BC = in_sizes[0] / (H * W);        // 32

    dim3 block(256);
    dim3 grid(W / TILE_X, H / TILE_Y, BC);       // 8 x 16 x 32 = 4096 blocks

    bilat3_fused<<<grid, block, 0, stream>>>(x, out, sxyz, sr, H, W);
}